// Round 6
// baseline (969.522 us; speedup 1.0000x reference)
//
#include <hip/hip_runtime.h>

#define B_ 16
#define N_ 16384
#define K_ 16

// ---- compact workspace layout (float offsets); total 56928 floats = 222 KB ----
enum : int {
  WS_LAT  = 0,      // 32 x 128 latent (f32, atomicMax-as-uint, relu>=0)
  WS_KPP  = 4096,   // 32 x 48 proposed keypoints
  WS_SEL  = 5632,   // 32 x 48 selected keypoints
  WS_PMIN = 7168,   // 16 x 3
  WS_PMAX = 7216,   // 16 x 3
  WS_CF   = 7264,   // 16 x 512 x 3 cage corners
  WS_W1F  = 31840,  // 64 x 3  bn-folded
  WS_B1F  = 32032,  // 64
  WS_W2F  = 32096,  // 128 x 64 bn-folded
  WS_B2F  = 40288,  // 128
  WS_W3F  = 40416,  // 128(c_in) x 128(out), transposed, scale3-folded
  WS_B3F  = 56800,  // 128
  WS_END  = 56928
};

enum : int { OUT_DEF=0, OUT_SRCKP=786432, OUT_TGTKP=787200 };

__device__ __forceinline__ float dist2rn(float px,float py,float pz,float sx,float sy,float sz){
  float dx=__fsub_rn(px,sx), dy=__fsub_rn(py,sy), dz=__fsub_rn(pz,sz);
  return __fadd_rn(__fadd_rn(__fmul_rn(dx,dx),__fmul_rn(dy,dy)),__fmul_rn(dz,dz));
}

// ---------------- prep: fold BN into encoder weights, w3 transposed -----------
struct EncW {
  const float *w1,*b1,*g1,*be1,*m1,*v1;
  const float *w2,*b2,*g2,*be2,*m2,*v2;
  const float *w3,*b3,*g3,*be3,*m3,*v3;
};

__device__ __forceinline__ float bn_scale(const float* g, const float* v, int ch){
  return g[ch] * (1.0f / sqrtf(v[ch] + 1e-5f));
}

__global__ void prep_kernel(EncW a, float* ws){
  const int stride = gridDim.x*blockDim.x;
  const int tid = blockIdx.x*blockDim.x + threadIdx.x;
  for (int i=tid;i<4096;i+=stride)            // zero latent (atomicMax target)
    ws[WS_LAT+i] = 0.0f;
  for (int i=tid;i<192;i+=stride){            // W1F
    int o=i/3;
    ws[WS_W1F+i] = a.w1[i] * bn_scale(a.g1,a.v1,o);
  }
  for (int i=tid;i<64;i+=stride){             // B1F = (b1-m1)*s1+be1
    float s = bn_scale(a.g1,a.v1,i);
    ws[WS_B1F+i] = (a.b1[i] - a.m1[i])*s + a.be1[i];
  }
  for (int i=tid;i<8192;i+=stride){           // W2F
    int o=i>>6;
    ws[WS_W2F+i] = a.w2[i] * bn_scale(a.g2,a.v2,o);
  }
  for (int i=tid;i<128;i+=stride){
    float s = bn_scale(a.g2,a.v2,i);
    ws[WS_B2F+i] = (a.b2[i] - a.m2[i])*s + a.be2[i];
  }
  for (int i=tid;i<16384;i+=stride){          // W3F[c][j] = w3[j][c]*s3[j]
    int c=i>>7, j=i&127;
    ws[WS_W3F+i] = a.w3[j*128+c] * bn_scale(a.g3,a.v3,j);
  }
  for (int i=tid;i<128;i+=stride){
    float s = bn_scale(a.g3,a.v3,i);
    ws[WS_B3F+i] = (a.b3[i] - a.m3[i])*s + a.be3[i];
  }
}

// ---------------- encoder v2: channel-split tiled GEMM ------------------------
// R4/R5 post-mortem: per-thread acc3[128] forced ~100 arch VGPR + 128 AGPR
// (2 waves/SIMD, v_accvgpr shuttle per FMA, VALUBusy 44%). v2 splits the 128
// output channels across the block's 4 waves (32 acc regs/thread) and
// broadcasts activations via LDS; weights stay wave-uniform scalar loads.
// Tile = 64 points (lane = point), LDS = h1 16KB + h2 32KB = 48KB -> 3 blk/CU.
__global__ __launch_bounds__(256) void encode_kernel(const float* __restrict__ src,
                                                     const float* __restrict__ tgt,
                                                     const float* __restrict__ ws,
                                                     float* __restrict__ lat){
  const int cloud = blockIdx.y;
  const int tile  = blockIdx.x;              // 0..255 (64 points each)
  const int t = threadIdx.x;
  const int lane = t & 63;
  const int wv = __builtin_amdgcn_readfirstlane(t >> 6);   // 0..3, wave-uniform

  const float* base = ((cloud < B_) ? (src + (size_t)cloud*N_*3)
                                    : (tgt + (size_t)(cloud-B_)*N_*3))
                      + (size_t)tile*64*3;

  __shared__ float h1s[64*64];    // [ch][pt]
  __shared__ float h2s[128*64];   // [ch][pt]

  // phase A: layer 1 (3 -> 64), each wave does 16 channels for 64 points
  {
    const float x0 = base[lane*3+0];
    const float x1 = base[lane*3+1];
    const float x2 = base[lane*3+2];
    const float* w1 = ws + WS_W1F;
    #pragma unroll
    for (int k=0;k<16;k++){
      const int o = wv*16 + k;
      float acc = fmaf(w1[o*3+2], x2, fmaf(w1[o*3+1], x1, w1[o*3]*x0)) + ws[WS_B1F+o];
      h1s[o*64 + lane] = fmaxf(acc, 0.0f);
    }
  }
  __syncthreads();

  // phase B: layer 2 (64 -> 128), wave wv owns channels 32wv..32wv+31
  {
    float acc[32];
    const float* w2 = ws + WS_W2F + wv*32*64;
    #pragma unroll
    for (int oo=0;oo<32;oo++) acc[oo] = 0.0f;
    #pragma unroll 2
    for (int c=0;c<64;c++){
      const float v = h1s[c*64 + lane];
      #pragma unroll
      for (int oo=0;oo<32;oo++)
        acc[oo] = fmaf(w2[oo*64 + c], v, acc[oo]);
    }
    #pragma unroll
    for (int oo=0;oo<32;oo++)
      h2s[(wv*32+oo)*64 + lane] = fmaxf(acc[oo] + ws[WS_B2F + wv*32 + oo], 0.0f);
  }
  __syncthreads();

  // phase C: layer 3 (128 -> 128), wave wv owns channels 32wv..32wv+31
  {
    float acc[32];
    const float* w3 = ws + WS_W3F;    // [c][j], j-contiguous
    #pragma unroll
    for (int jj=0;jj<32;jj++) acc[jj] = 0.0f;
    #pragma unroll 2
    for (int o=0;o<128;o++){
      const float v = h2s[o*64 + lane];
      #pragma unroll
      for (int jj=0;jj<32;jj++)
        acc[jj] = fmaf(w3[o*128 + wv*32 + jj], v, acc[jj]);
    }
    // relu, max over the 64 points of this tile, one atomic per channel
    #pragma unroll
    for (int jj=0;jj<32;jj++){
      float x = fmaxf(acc[jj] + ws[WS_B3F + wv*32 + jj], 0.0f);  // >=0 -> uint order ok
      #pragma unroll
      for (int off=32; off>0; off>>=1) x = fmaxf(x, __shfl_down(x, off, 64));
      if (lane==0)
        atomicMax((unsigned*)(lat + cloud*128 + wv*32 + jj), __float_as_uint(x));
    }
  }
}

// ---------------- keypoint MLP: lat(128) -> 128 relu -> 48 --------------------
__global__ void kp_mlp_kernel(const float* __restrict__ ws,
                              const float* __restrict__ kw1, const float* __restrict__ kb1,
                              const float* __restrict__ kw2, const float* __restrict__ kb2,
                              float* __restrict__ wsm){
  const int cloud = blockIdx.x; const int t = threadIdx.x;
  __shared__ float h[128];
  const float* lat = ws + WS_LAT + cloud*128;
  if (t < 128){
    float acc = kb1[t];
    const float* w = kw1 + t*128;
    for (int c=0;c<128;c++) acc = fmaf(lat[c], w[c], acc);
    h[t] = fmaxf(acc, 0.0f);
  }
  __syncthreads();
  if (t < 48){
    float acc = kb2[t];
    const float* w = kw2 + t*128;
    for (int c=0;c<128;c++) acc = fmaf(h[c], w[c], acc);
    wsm[WS_KPP + cloud*48 + t] = acc;
  }
}

// ---------------- FPS (one block per cloud) -----------------------------------
__device__ int block_argmax(float v, int i, float* rv, int* ri, int t){
  __syncthreads();
  rv[t]=v; ri[t]=i;
  __syncthreads();
  for (int s=128; s>0; s>>=1){
    if (t < s){
      float v2 = rv[t+s]; int i2 = ri[t+s];
      if (v2 > rv[t] || (v2 == rv[t] && i2 < ri[t])){ rv[t]=v2; ri[t]=i2; }
    }
    __syncthreads();
  }
  return ri[0];   // first-index-on-tie == numpy argmax
}

__global__ __launch_bounds__(256) void fps_kernel(const float* __restrict__ src,
                                                  const float* __restrict__ tgt,
                                                  float* ws, float* out){
  const int cloud = blockIdx.x; const int t = threadIdx.x;
  const float* base = (cloud < B_) ? (src + (size_t)cloud*N_*3)
                                   : (tgt + (size_t)(cloud-B_)*N_*3);
  __shared__ float rv[256]; __shared__ int ri[256]; __shared__ float sel[3];
  const float* kp = ws + WS_KPP + cloud*48;

  // phase A: d0 = min over proposed kps, argmax
  float bv = -1.0f; int bi = 0;
  for (int k=0;k<64;k++){
    int n = t + k*256;
    float px=base[n*3], py=base[n*3+1], pz=base[n*3+2];
    float dmin = 3.4028235e38f;
    #pragma unroll
    for (int j=0;j<K_;j++)
      dmin = fminf(dmin, dist2rn(px,py,pz, kp[j*3],kp[j*3+1],kp[j*3+2]));
    if (dmin > bv){ bv = dmin; bi = n; }
  }
  int idx = block_argmax(bv, bi, rv, ri, t);
  if (t==0){ sel[0]=base[idx*3]; sel[1]=base[idx*3+1]; sel[2]=base[idx*3+2]; }
  __syncthreads();
  float s0=sel[0], s1=sel[1], s2=sel[2];
  if (t==0){
    float* sw = ws + WS_SEL + cloud*48;
    sw[0]=s0; sw[1]=s1; sw[2]=s2;
    size_t o = (cloud<B_) ? (size_t)(OUT_SRCKP + cloud*48) : (size_t)(OUT_TGTKP + (cloud-B_)*48);
    out[o]=s0; out[o+1]=s1; out[o+2]=s2;
  }

  // phase B: mind = dist to sel0 (fresh, per reference), track argmax
  float mind[64];
  bv = -1.0f; bi = 0;
  #pragma unroll
  for (int k=0;k<64;k++){
    int n = t + k*256;
    float px=base[n*3], py=base[n*3+1], pz=base[n*3+2];
    float d = dist2rn(px,py,pz, s0,s1,s2);
    mind[k]=d;
    if (d > bv){ bv=d; bi=n; }
  }

  for (int it=1; it<K_; it++){
    idx = block_argmax(bv, bi, rv, ri, t);
    if (t==0){ sel[0]=base[idx*3]; sel[1]=base[idx*3+1]; sel[2]=base[idx*3+2]; }
    __syncthreads();
    s0=sel[0]; s1=sel[1]; s2=sel[2];
    if (t==0){
      float* sw = ws + WS_SEL + cloud*48 + it*3;
      sw[0]=s0; sw[1]=s1; sw[2]=s2;
      size_t o = (cloud<B_) ? (size_t)(OUT_SRCKP + cloud*48 + it*3) : (size_t)(OUT_TGTKP + (cloud-B_)*48 + it*3);
      out[o]=s0; out[o+1]=s1; out[o+2]=s2;
    }
    if (it < K_-1){
      bv=-1.0f; bi=0;
      #pragma unroll
      for (int k=0;k<64;k++){
        int n = t + k*256;
        float px=base[n*3], py=base[n*3+1], pz=base[n*3+2];
        float d = dist2rn(px,py,pz, s0,s1,s2);
        float m = fminf(mind[k], d);
        mind[k]=m;
        if (m > bv){ bv=m; bi=n; }
      }
    }
  }
}

// ---------------- per-batch source min/max ------------------------------------
__global__ void pminmax_kernel(const float* __restrict__ src, float* ws){
  __shared__ float red[256];
  const int b=blockIdx.x, t=threadIdx.x;
  const float* base = src + (size_t)b*N_*3;
  float mn[3]={3.4e38f,3.4e38f,3.4e38f}, mx[3]={-3.4e38f,-3.4e38f,-3.4e38f};
  for (int n=t;n<N_;n+=256){
    #pragma unroll
    for (int c=0;c<3;c++){
      float v=base[n*3+c];
      mn[c]=fminf(mn[c],v); mx[c]=fmaxf(mx[c],v);
    }
  }
  for (int c=0;c<3;c++){
    red[t]=mn[c]; __syncthreads();
    for (int s=128;s>0;s>>=1){ if(t<s) red[t]=fminf(red[t],red[t+s]); __syncthreads(); }
    if (t==0) ws[WS_PMIN+b*3+c]=red[0];
    __syncthreads();
    red[t]=mx[c]; __syncthreads();
    for (int s=128;s>0;s>>=1){ if(t<s) red[t]=fmaxf(red[t],red[t+s]); __syncthreads(); }
    if (t==0) ws[WS_PMAX+b*3+c]=red[0];
    __syncthreads();
  }
}

// ---------------- cage MLP + corner grid --------------------------------------
__global__ void cage_mlp_kernel(const float* __restrict__ ws,
                                const float* __restrict__ cw1, const float* __restrict__ cb1,
                                const float* __restrict__ cw2, const float* __restrict__ cb2,
                                float* __restrict__ wsm){
  const int b = blockIdx.x; const int t = threadIdx.x;
  __shared__ float diff[48]; __shared__ float h[128];
  if (t<48) diff[t] = __fsub_rn(ws[WS_SEL + (B_+b)*48 + t], ws[WS_SEL + b*48 + t]);
  __syncthreads();
  if (t<128){
    const float* w = cw1 + t*48;
    float acc = cb1[t];
    for (int j=0;j<48;j++) acc = fmaf(diff[j], w[j], acc);
    h[t] = fmaxf(acc, 0.0f);
  }
  __syncthreads();
  for (int o=t;o<1536;o+=256){
    const float* w = cw2 + o*128;
    float acc = cb2[o];
    for (int c=0;c<128;c++) acc = fmaf(h[c], w[c], acc);
    int flat = o/3, coord = o - flat*3;
    int u = flat>>6, v=(flat>>3)&7, z=flat&7;
    int g = (coord==0)?u:((coord==1)?v:z);
    float gv = (g==7)?1.0f:(float)g*(1.0f/7.0f);
    wsm[WS_CF + b*1536 + o] = gv + acc;
  }
}

// ---------------- trilinear cage deform ---------------------------------------
__global__ __launch_bounds__(256) void deform_kernel(const float* __restrict__ src,
                                                     const float* __restrict__ ws,
                                                     float* __restrict__ out){
  const int b = blockIdx.y;
  const int n = blockIdx.x*256 + threadIdx.x;
  __shared__ float cf[1536];
  for (int i=threadIdx.x;i<1536;i+=256) cf[i] = ws[WS_CF + b*1536 + i];
  __syncthreads();

  const float* p = src + ((size_t)b*N_ + n)*3;
  float pt[3]; int id[3]; float w[3];
  #pragma unroll
  for (int c=0;c<3;c++){
    float pv = p[c];
    float mn = ws[WS_PMIN+b*3+c], mxv = ws[WS_PMAX+b*3+c];
    float denom = __fadd_rn(__fsub_rn(mxv, mn), 1e-6f);
    float tc = __fmul_rn(__fdiv_rn(__fsub_rn(pv, mn), denom), 7.0f);
    int ic = (int)tc; ic = min(max(ic,0),6);
    pt[c]=pv; id[c]=ic; w[c]=__fsub_rn(tc, (float)ic);
  }
  const int flat = (id[0]<<6) + (id[1]<<3) + id[2];
  const float* c000 = cf + flat*3;
  const float wx=w[0], wy=w[1], wz=w[2];
  const float ux=__fsub_rn(1.0f,wx), uy=__fsub_rn(1.0f,wy), uz=__fsub_rn(1.0f,wz);
  const float w000=__fmul_rn(__fmul_rn(ux,uy),uz);
  const float w100=__fmul_rn(__fmul_rn(wx,uy),uz);
  const float w010=__fmul_rn(__fmul_rn(ux,wy),uz);
  const float w110=__fmul_rn(__fmul_rn(wx,wy),uz);
  const float w001=__fmul_rn(__fmul_rn(ux,uy),wz);
  const float w101=__fmul_rn(__fmul_rn(wx,uy),wz);
  const float w011=__fmul_rn(__fmul_rn(ux,wy),wz);
  const float w111=__fmul_rn(__fmul_rn(wx,wy),wz);
  #pragma unroll
  for (int c=0;c<3;c++){
    float d = __fmul_rn(w000, c000[c]);
    d = __fadd_rn(d, __fmul_rn(w100, c000[192+c]));  // (+1,0,0) -> +64*3
    d = __fadd_rn(d, __fmul_rn(w010, c000[24+c]));   // (0,+1,0) -> +8*3
    d = __fadd_rn(d, __fmul_rn(w110, c000[216+c]));
    d = __fadd_rn(d, __fmul_rn(w001, c000[3+c]));    // (0,0,+1) -> +3
    d = __fadd_rn(d, __fmul_rn(w101, c000[195+c]));
    d = __fadd_rn(d, __fmul_rn(w011, c000[27+c]));
    d = __fadd_rn(d, __fmul_rn(w111, c000[219+c]));
    out[((size_t)b*N_+n)*3 + c] = __fadd_rn(pt[c], d);
  }
}

// ---------------- launch ------------------------------------------------------
extern "C" void kernel_launch(void* const* d_in, const int* in_sizes, int n_in,
                              void* d_out, int out_size, void* d_ws, size_t ws_size,
                              hipStream_t stream){
  const float* src = (const float*)d_in[0];
  const float* tgt = (const float*)d_in[1];
  float* ws = (float*)d_ws;
  float* out = (float*)d_out;

  EncW ew;
  ew.w1 =(const float*)d_in[2];  ew.b1 =(const float*)d_in[3];
  ew.g1 =(const float*)d_in[4];  ew.be1=(const float*)d_in[5];
  ew.m1 =(const float*)d_in[6];  ew.v1 =(const float*)d_in[7];
  ew.w2 =(const float*)d_in[8];  ew.b2 =(const float*)d_in[9];
  ew.g2 =(const float*)d_in[10]; ew.be2=(const float*)d_in[11];
  ew.m2 =(const float*)d_in[12]; ew.v2 =(const float*)d_in[13];
  ew.w3 =(const float*)d_in[14]; ew.b3 =(const float*)d_in[15];
  ew.g3 =(const float*)d_in[16]; ew.be3=(const float*)d_in[17];
  ew.m3 =(const float*)d_in[18]; ew.v3 =(const float*)d_in[19];

  prep_kernel<<<128, 256, 0, stream>>>(ew, ws);
  encode_kernel<<<dim3(256,32), 256, 0, stream>>>(src, tgt, ws, ws + WS_LAT);
  kp_mlp_kernel<<<32, 128, 0, stream>>>(ws,
      (const float*)d_in[20], (const float*)d_in[21],
      (const float*)d_in[22], (const float*)d_in[23], ws);
  fps_kernel<<<32, 256, 0, stream>>>(src, tgt, ws, out);
  pminmax_kernel<<<16, 256, 0, stream>>>(src, ws);
  cage_mlp_kernel<<<16, 256, 0, stream>>>(ws,
      (const float*)d_in[24], (const float*)d_in[25],
      (const float*)d_in[26], (const float*)d_in[27], ws);
  deform_kernel<<<dim3(64,16), 256, 0, stream>>>(src, ws, out);
}

// Round 7
// 769.012 us; speedup vs baseline: 1.2607x; 1.2607x over previous
//
#include <hip/hip_runtime.h>

#define B_ 16
#define N_ 16384
#define K_ 16

// ---- compact workspace layout (float offsets); total 56928 floats = 222 KB ----
enum : int {
  WS_LAT  = 0,      // 32 x 128 latent (f32, atomicMax-as-uint, relu>=0)
  WS_KPP  = 4096,   // 32 x 48 proposed keypoints
  WS_SEL  = 5632,   // 32 x 48 selected keypoints
  WS_PMIN = 7168,   // 16 x 3
  WS_PMAX = 7216,   // 16 x 3
  WS_CF   = 7264,   // 16 x 512 x 3 cage corners
  WS_W1F  = 31840,  // 64 x 3  bn-folded
  WS_B1F  = 32032,  // 64
  WS_W2T  = 32096,  // 64(c_in) x 128(out) TRANSPOSED, bn-folded
  WS_B2F  = 40288,  // 128
  WS_W3F  = 40416,  // 128(c_in) x 128(out), transposed, scale3-folded
  WS_B3F  = 56800,  // 128
  WS_END  = 56928
};

enum : int { OUT_DEF=0, OUT_SRCKP=786432, OUT_TGTKP=787200 };

__device__ __forceinline__ float dist2rn(float px,float py,float pz,float sx,float sy,float sz){
  float dx=__fsub_rn(px,sx), dy=__fsub_rn(py,sy), dz=__fsub_rn(pz,sz);
  return __fadd_rn(__fadd_rn(__fmul_rn(dx,dx),__fmul_rn(dy,dy)),__fmul_rn(dz,dz));
}

// ---------------- prep: fold BN into encoder weights, transpose w2/w3 ---------
struct EncW {
  const float *w1,*b1,*g1,*be1,*m1,*v1;
  const float *w2,*b2,*g2,*be2,*m2,*v2;
  const float *w3,*b3,*g3,*be3,*m3,*v3;
};

__device__ __forceinline__ float bn_scale(const float* g, const float* v, int ch){
  return g[ch] * (1.0f / sqrtf(v[ch] + 1e-5f));
}

__global__ void prep_kernel(EncW a, float* ws){
  const int stride = gridDim.x*blockDim.x;
  const int tid = blockIdx.x*blockDim.x + threadIdx.x;
  for (int i=tid;i<4096;i+=stride)            // zero latent (atomicMax target)
    ws[WS_LAT+i] = 0.0f;
  for (int i=tid;i<192;i+=stride){            // W1F
    int o=i/3;
    ws[WS_W1F+i] = a.w1[i] * bn_scale(a.g1,a.v1,o);
  }
  for (int i=tid;i<64;i+=stride){             // B1F = (b1-m1)*s1+be1
    float s = bn_scale(a.g1,a.v1,i);
    ws[WS_B1F+i] = (a.b1[i] - a.m1[i])*s + a.be1[i];
  }
  for (int i=tid;i<8192;i+=stride){           // W2T[c][o] = w2[o][c]*s2[o]
    int c=i>>7, o=i&127;
    ws[WS_W2T+i] = a.w2[o*64+c] * bn_scale(a.g2,a.v2,o);
  }
  for (int i=tid;i<128;i+=stride){
    float s = bn_scale(a.g2,a.v2,i);
    ws[WS_B2F+i] = (a.b2[i] - a.m2[i])*s + a.be2[i];
  }
  for (int i=tid;i<16384;i+=stride){          // W3F[c][j] = w3[j][c]*s3[j]
    int c=i>>7, j=i&127;
    ws[WS_W3F+i] = a.w3[j*128+c] * bn_scale(a.g3,a.v3,j);
  }
  for (int i=tid;i<128;i+=stride){
    float s = bn_scale(a.g3,a.v3,i);
    ws[WS_B3F+i] = (a.b3[i] - a.m3[i])*s + a.be3[i];
  }
}

// ---------------- encoder v3: P=2 pts/lane, input-major weights ---------------
// R6 post-mortem: v2 was scalar-load bound (1 s_load per FMA in phase B,
// strided w2 access) + lgkmcnt mixing. v3: W2 transposed (contiguous 16-weight
// rows -> s_load_dwordx8), P=2 points/lane doubles FMAs per weight load,
// h2 staged in two 64-channel half-passes (LDS 64KB -> 2 blocks/CU).
// Per-wave: B: 64c x (1 ds_read_b64 + 2 s_loadx8 + 32 fmac);
//           C: 64c x (1 ds_read_b64 + 4 s_loadx8 + 64 fmac).  FMA floor 164us.
__global__ __launch_bounds__(256, 2) void encode_kernel(const float* __restrict__ src,
                                                        const float* __restrict__ tgt,
                                                        const float* __restrict__ ws,
                                                        float* __restrict__ lat){
  const int cloud = blockIdx.y;
  const int tile  = blockIdx.x;              // 128 tiles/cloud, 128 pts each
  const int t = threadIdx.x;
  const int lane = t & 63;
  const int wv = __builtin_amdgcn_readfirstlane(t >> 6);   // 0..3

  const float* base = ((cloud < B_) ? (src + (size_t)cloud*N_*3)
                                    : (tgt + (size_t)(cloud-B_)*N_*3))
                      + (size_t)tile*128*3;

  __shared__ float h1s[64*128];   // [c][pt]  32KB
  __shared__ float h2a[64*128];   // [half-ch][pt] 32KB (reused across passes)

  const int p0 = 2*lane;
  const float x0a=base[p0*3+0], x1a=base[p0*3+1], x2a=base[p0*3+2];
  const float x0b=base[p0*3+3], x1b=base[p0*3+4], x2b=base[p0*3+5];

  // phase A: layer 1 (3->64); wave wv computes channels 16wv..16wv+15
  {
    const float* w1 = ws + WS_W1F;
    #pragma unroll
    for (int k=0;k<16;k++){
      const int o = wv*16 + k;
      const float wx=w1[o*3], wy=w1[o*3+1], wz=w1[o*3+2], bb=ws[WS_B1F+o];
      const float ya = fmaxf(fmaf(wz,x2a,fmaf(wy,x1a,wx*x0a))+bb, 0.0f);
      const float yb = fmaxf(fmaf(wz,x2b,fmaf(wy,x1b,wx*x0b))+bb, 0.0f);
      h1s[o*128+p0]   = ya;
      h1s[o*128+p0+1] = yb;
    }
  }
  __syncthreads();

  float accL[2][32];
  #pragma unroll
  for (int jj=0;jj<32;jj++){ accL[0][jj]=0.0f; accL[1][jj]=0.0f; }

  #pragma unroll 1
  for (int pass=0; pass<2; pass++){
    // phase B: h2 channels [pass*64 + wv*16, +16) for this lane's 2 points
    float acc[2][16];
    #pragma unroll
    for (int oo=0;oo<16;oo++){ acc[0][oo]=0.0f; acc[1][oo]=0.0f; }
    const float* w2t = ws + WS_W2T + pass*64 + wv*16;   // + c*128 + oo
    for (int c=0;c<64;c++){
      const float2 a = *(const float2*)&h1s[c*128 + p0];
      #pragma unroll
      for (int oo=0;oo<16;oo++){
        const float w = w2t[c*128 + oo];
        acc[0][oo] = fmaf(a.x, w, acc[0][oo]);
        acc[1][oo] = fmaf(a.y, w, acc[1][oo]);
      }
    }
    __syncthreads();   // pass1: all waves done READING h2a before overwrite
    #pragma unroll
    for (int oo=0;oo<16;oo++){
      const float b = ws[WS_B2F + pass*64 + wv*16 + oo];
      float2 y;
      y.x = fmaxf(acc[0][oo]+b, 0.0f);
      y.y = fmaxf(acc[1][oo]+b, 0.0f);
      *(float2*)&h2a[(wv*16+oo)*128 + p0] = y;
    }
    __syncthreads();

    // phase C: layer-3 partial over this half's 64 input channels
    for (int c2=0;c2<64;c2++){
      const float2 a = *(const float2*)&h2a[c2*128 + p0];
      const float* wr = ws + WS_W3F + (pass*64+c2)*128 + wv*32;
      #pragma unroll
      for (int jj=0;jj<32;jj++){
        const float w = wr[jj];
        accL[0][jj] = fmaf(a.x, w, accL[0][jj]);
        accL[1][jj] = fmaf(a.y, w, accL[1][jj]);
      }
    }
    __syncthreads();   // all waves done reading h2a before next pass writes
  }

  // bias+relu, max over this lane's 2 pts, wave-reduce 64 pts... 128-pt tile,
  // then one atomic per channel (wave wv owns latent channels 32wv..32wv+31)
  #pragma unroll
  for (int jj=0;jj<32;jj++){
    const float b = ws[WS_B3F + wv*32 + jj];
    float x = fmaxf(fmaxf(accL[0][jj]+b, 0.0f), fmaxf(accL[1][jj]+b, 0.0f));
    #pragma unroll
    for (int off=32; off>0; off>>=1) x = fmaxf(x, __shfl_down(x, off, 64));
    if (lane==0)
      atomicMax((unsigned*)(lat + cloud*128 + wv*32 + jj), __float_as_uint(x));
  }
}

// ---------------- keypoint MLP: lat(128) -> 128 relu -> 48 --------------------
__global__ void kp_mlp_kernel(const float* __restrict__ ws,
                              const float* __restrict__ kw1, const float* __restrict__ kb1,
                              const float* __restrict__ kw2, const float* __restrict__ kb2,
                              float* __restrict__ wsm){
  const int cloud = blockIdx.x; const int t = threadIdx.x;
  __shared__ float h[128];
  const float* lat = ws + WS_LAT + cloud*128;
  if (t < 128){
    float acc = kb1[t];
    const float* w = kw1 + t*128;
    for (int c=0;c<128;c++) acc = fmaf(lat[c], w[c], acc);
    h[t] = fmaxf(acc, 0.0f);
  }
  __syncthreads();
  if (t < 48){
    float acc = kb2[t];
    const float* w = kw2 + t*128;
    for (int c=0;c<128;c++) acc = fmaf(h[c], w[c], acc);
    wsm[WS_KPP + cloud*48 + t] = acc;
  }
}

// ---------------- FPS (one block per cloud) -----------------------------------
__device__ int block_argmax(float v, int i, float* rv, int* ri, int t){
  __syncthreads();
  rv[t]=v; ri[t]=i;
  __syncthreads();
  for (int s=128; s>0; s>>=1){
    if (t < s){
      float v2 = rv[t+s]; int i2 = ri[t+s];
      if (v2 > rv[t] || (v2 == rv[t] && i2 < ri[t])){ rv[t]=v2; ri[t]=i2; }
    }
    __syncthreads();
  }
  return ri[0];   // first-index-on-tie == numpy argmax
}

__global__ __launch_bounds__(256) void fps_kernel(const float* __restrict__ src,
                                                  const float* __restrict__ tgt,
                                                  float* ws, float* out){
  const int cloud = blockIdx.x; const int t = threadIdx.x;
  const float* base = (cloud < B_) ? (src + (size_t)cloud*N_*3)
                                   : (tgt + (size_t)(cloud-B_)*N_*3);
  __shared__ float rv[256]; __shared__ int ri[256]; __shared__ float sel[3];
  const float* kp = ws + WS_KPP + cloud*48;

  // phase A: d0 = min over proposed kps, argmax
  float bv = -1.0f; int bi = 0;
  for (int k=0;k<64;k++){
    int n = t + k*256;
    float px=base[n*3], py=base[n*3+1], pz=base[n*3+2];
    float dmin = 3.4028235e38f;
    #pragma unroll
    for (int j=0;j<K_;j++)
      dmin = fminf(dmin, dist2rn(px,py,pz, kp[j*3],kp[j*3+1],kp[j*3+2]));
    if (dmin > bv){ bv = dmin; bi = n; }
  }
  int idx = block_argmax(bv, bi, rv, ri, t);
  if (t==0){ sel[0]=base[idx*3]; sel[1]=base[idx*3+1]; sel[2]=base[idx*3+2]; }
  __syncthreads();
  float s0=sel[0], s1=sel[1], s2=sel[2];
  if (t==0){
    float* sw = ws + WS_SEL + cloud*48;
    sw[0]=s0; sw[1]=s1; sw[2]=s2;
    size_t o = (cloud<B_) ? (size_t)(OUT_SRCKP + cloud*48) : (size_t)(OUT_TGTKP + (cloud-B_)*48);
    out[o]=s0; out[o+1]=s1; out[o+2]=s2;
  }

  // phase B: mind = dist to sel0 (fresh, per reference), track argmax
  float mind[64];
  bv = -1.0f; bi = 0;
  #pragma unroll
  for (int k=0;k<64;k++){
    int n = t + k*256;
    float px=base[n*3], py=base[n*3+1], pz=base[n*3+2];
    float d = dist2rn(px,py,pz, s0,s1,s2);
    mind[k]=d;
    if (d > bv){ bv=d; bi=n; }
  }

  for (int it=1; it<K_; it++){
    idx = block_argmax(bv, bi, rv, ri, t);
    if (t==0){ sel[0]=base[idx*3]; sel[1]=base[idx*3+1]; sel[2]=base[idx*3+2]; }
    __syncthreads();
    s0=sel[0]; s1=sel[1]; s2=sel[2];
    if (t==0){
      float* sw = ws + WS_SEL + cloud*48 + it*3;
      sw[0]=s0; sw[1]=s1; sw[2]=s2;
      size_t o = (cloud<B_) ? (size_t)(OUT_SRCKP + cloud*48 + it*3) : (size_t)(OUT_TGTKP + (cloud-B_)*48 + it*3);
      out[o]=s0; out[o+1]=s1; out[o+2]=s2;
    }
    if (it < K_-1){
      bv=-1.0f; bi=0;
      #pragma unroll
      for (int k=0;k<64;k++){
        int n = t + k*256;
        float px=base[n*3], py=base[n*3+1], pz=base[n*3+2];
        float d = dist2rn(px,py,pz, s0,s1,s2);
        float m = fminf(mind[k], d);
        mind[k]=m;
        if (m > bv){ bv=m; bi=n; }
      }
    }
  }
}

// ---------------- per-batch source min/max ------------------------------------
__global__ void pminmax_kernel(const float* __restrict__ src, float* ws){
  __shared__ float red[256];
  const int b=blockIdx.x, t=threadIdx.x;
  const float* base = src + (size_t)b*N_*3;
  float mn[3]={3.4e38f,3.4e38f,3.4e38f}, mx[3]={-3.4e38f,-3.4e38f,-3.4e38f};
  for (int n=t;n<N_;n+=256){
    #pragma unroll
    for (int c=0;c<3;c++){
      float v=base[n*3+c];
      mn[c]=fminf(mn[c],v); mx[c]=fmaxf(mx[c],v);
    }
  }
  for (int c=0;c<3;c++){
    red[t]=mn[c]; __syncthreads();
    for (int s=128;s>0;s>>=1){ if(t<s) red[t]=fminf(red[t],red[t+s]); __syncthreads(); }
    if (t==0) ws[WS_PMIN+b*3+c]=red[0];
    __syncthreads();
    red[t]=mx[c]; __syncthreads();
    for (int s=128;s>0;s>>=1){ if(t<s) red[t]=fmaxf(red[t],red[t+s]); __syncthreads(); }
    if (t==0) ws[WS_PMAX+b*3+c]=red[0];
    __syncthreads();
  }
}

// ---------------- cage MLP + corner grid --------------------------------------
__global__ void cage_mlp_kernel(const float* __restrict__ ws,
                                const float* __restrict__ cw1, const float* __restrict__ cb1,
                                const float* __restrict__ cw2, const float* __restrict__ cb2,
                                float* __restrict__ wsm){
  const int b = blockIdx.x; const int t = threadIdx.x;
  __shared__ float diff[48]; __shared__ float h[128];
  if (t<48) diff[t] = __fsub_rn(ws[WS_SEL + (B_+b)*48 + t], ws[WS_SEL + b*48 + t]);
  __syncthreads();
  if (t<128){
    const float* w = cw1 + t*48;
    float acc = cb1[t];
    for (int j=0;j<48;j++) acc = fmaf(diff[j], w[j], acc);
    h[t] = fmaxf(acc, 0.0f);
  }
  __syncthreads();
  for (int o=t;o<1536;o+=256){
    const float* w = cw2 + o*128;
    float acc = cb2[o];
    for (int c=0;c<128;c++) acc = fmaf(h[c], w[c], acc);
    int flat = o/3, coord = o - flat*3;
    int u = flat>>6, v=(flat>>3)&7, z=flat&7;
    int g = (coord==0)?u:((coord==1)?v:z);
    float gv = (g==7)?1.0f:(float)g*(1.0f/7.0f);
    wsm[WS_CF + b*1536 + o] = gv + acc;
  }
}

// ---------------- trilinear cage deform ---------------------------------------
__global__ __launch_bounds__(256) void deform_kernel(const float* __restrict__ src,
                                                     const float* __restrict__ ws,
                                                     float* __restrict__ out){
  const int b = blockIdx.y;
  const int n = blockIdx.x*256 + threadIdx.x;
  __shared__ float cf[1536];
  for (int i=threadIdx.x;i<1536;i+=256) cf[i] = ws[WS_CF + b*1536 + i];
  __syncthreads();

  const float* p = src + ((size_t)b*N_ + n)*3;
  float pt[3]; int id[3]; float w[3];
  #pragma unroll
  for (int c=0;c<3;c++){
    float pv = p[c];
    float mn = ws[WS_PMIN+b*3+c], mxv = ws[WS_PMAX+b*3+c];
    float denom = __fadd_rn(__fsub_rn(mxv, mn), 1e-6f);
    float tc = __fmul_rn(__fdiv_rn(__fsub_rn(pv, mn), denom), 7.0f);
    int ic = (int)tc; ic = min(max(ic,0),6);
    pt[c]=pv; id[c]=ic; w[c]=__fsub_rn(tc, (float)ic);
  }
  const int flat = (id[0]<<6) + (id[1]<<3) + id[2];
  const float* c000 = cf + flat*3;
  const float wx=w[0], wy=w[1], wz=w[2];
  const float ux=__fsub_rn(1.0f,wx), uy=__fsub_rn(1.0f,wy), uz=__fsub_rn(1.0f,wz);
  const float w000=__fmul_rn(__fmul_rn(ux,uy),uz);
  const float w100=__fmul_rn(__fmul_rn(wx,uy),uz);
  const float w010=__fmul_rn(__fmul_rn(ux,wy),uz);
  const float w110=__fmul_rn(__fmul_rn(wx,wy),uz);
  const float w001=__fmul_rn(__fmul_rn(ux,uy),wz);
  const float w101=__fmul_rn(__fmul_rn(wx,uy),wz);
  const float w011=__fmul_rn(__fmul_rn(ux,wy),wz);
  const float w111=__fmul_rn(__fmul_rn(wx,wy),wz);
  #pragma unroll
  for (int c=0;c<3;c++){
    float d = __fmul_rn(w000, c000[c]);
    d = __fadd_rn(d, __fmul_rn(w100, c000[192+c]));  // (+1,0,0) -> +64*3
    d = __fadd_rn(d, __fmul_rn(w010, c000[24+c]));   // (0,+1,0) -> +8*3
    d = __fadd_rn(d, __fmul_rn(w110, c000[216+c]));
    d = __fadd_rn(d, __fmul_rn(w001, c000[3+c]));    // (0,0,+1) -> +3
    d = __fadd_rn(d, __fmul_rn(w101, c000[195+c]));
    d = __fadd_rn(d, __fmul_rn(w011, c000[27+c]));
    d = __fadd_rn(d, __fmul_rn(w111, c000[219+c]));
    out[((size_t)b*N_+n)*3 + c] = __fadd_rn(pt[c], d);
  }
}

// ---------------- launch ------------------------------------------------------
extern "C" void kernel_launch(void* const* d_in, const int* in_sizes, int n_in,
                              void* d_out, int out_size, void* d_ws, size_t ws_size,
                              hipStream_t stream){
  const float* src = (const float*)d_in[0];
  const float* tgt = (const float*)d_in[1];
  float* ws = (float*)d_ws;
  float* out = (float*)d_out;

  EncW ew;
  ew.w1 =(const float*)d_in[2];  ew.b1 =(const float*)d_in[3];
  ew.g1 =(const float*)d_in[4];  ew.be1=(const float*)d_in[5];
  ew.m1 =(const float*)d_in[6];  ew.v1 =(const float*)d_in[7];
  ew.w2 =(const float*)d_in[8];  ew.b2 =(const float*)d_in[9];
  ew.g2 =(const float*)d_in[10]; ew.be2=(const float*)d_in[11];
  ew.m2 =(const float*)d_in[12]; ew.v2 =(const float*)d_in[13];
  ew.w3 =(const float*)d_in[14]; ew.b3 =(const float*)d_in[15];
  ew.g3 =(const float*)d_in[16]; ew.be3=(const float*)d_in[17];
  ew.m3 =(const float*)d_in[18]; ew.v3 =(const float*)d_in[19];

  prep_kernel<<<128, 256, 0, stream>>>(ew, ws);
  encode_kernel<<<dim3(128,32), 256, 0, stream>>>(src, tgt, ws, ws + WS_LAT);
  kp_mlp_kernel<<<32, 128, 0, stream>>>(ws,
      (const float*)d_in[20], (const float*)d_in[21],
      (const float*)d_in[22], (const float*)d_in[23], ws);
  fps_kernel<<<32, 256, 0, stream>>>(src, tgt, ws, out);
  pminmax_kernel<<<16, 256, 0, stream>>>(src, ws);
  cage_mlp_kernel<<<16, 256, 0, stream>>>(ws,
      (const float*)d_in[24], (const float*)d_in[25],
      (const float*)d_in[26], (const float*)d_in[27], ws);
  deform_kernel<<<dim3(64,16), 256, 0, stream>>>(src, ws, out);
}

// Round 8
// 578.269 us; speedup vs baseline: 1.6766x; 1.3299x over previous
//
#include <hip/hip_runtime.h>

#define B_ 16
#define N_ 16384
#define K_ 16

// ---- compact workspace layout (float offsets) ----
enum : int {
  WS_LAT  = 0,      // 32 x 128 latent (f32, atomicMax-as-uint, relu>=0)
  WS_SEL  = 5632,   // 32 x 48 selected keypoints
  WS_PMIN = 7168,   // 16 x 3
  WS_PMAX = 7216,   // 16 x 3
  WS_CF   = 7264,   // 16 x 512 x 3 cage corners
  WS_W1F  = 31840,  // 64 x 3  bn-folded
  WS_B1F  = 32032,  // 64
  WS_W2T  = 32096,  // 64(c_in) x 128(out) TRANSPOSED, bn-folded
  WS_B2F  = 40288,  // 128
  WS_W3F  = 40416,  // 128(c_in) x 128(out), transposed, scale3-folded
  WS_B3F  = 56800,  // 128
  WS_END  = 56928
};

enum : int { OUT_DEF=0, OUT_SRCKP=786432, OUT_TGTKP=787200 };

__device__ __forceinline__ float dist2rn(float px,float py,float pz,float sx,float sy,float sz){
  float dx=__fsub_rn(px,sx), dy=__fsub_rn(py,sy), dz=__fsub_rn(pz,sz);
  return __fadd_rn(__fadd_rn(__fmul_rn(dx,dx),__fmul_rn(dy,dy)),__fmul_rn(dz,dz));
}

// ---------------- prep: fold BN into encoder weights, transpose w2/w3 ---------
struct EncW {
  const float *w1,*b1,*g1,*be1,*m1,*v1;
  const float *w2,*b2,*g2,*be2,*m2,*v2;
  const float *w3,*b3,*g3,*be3,*m3,*v3;
};

__device__ __forceinline__ float bn_scale(const float* g, const float* v, int ch){
  return g[ch] * (1.0f / sqrtf(v[ch] + 1e-5f));
}

__global__ void prep_kernel(EncW a, float* ws){
  const int stride = gridDim.x*blockDim.x;
  const int tid = blockIdx.x*blockDim.x + threadIdx.x;
  for (int i=tid;i<4096;i+=stride)            // zero latent (atomicMax target)
    ws[WS_LAT+i] = 0.0f;
  for (int i=tid;i<192;i+=stride){            // W1F
    int o=i/3;
    ws[WS_W1F+i] = a.w1[i] * bn_scale(a.g1,a.v1,o);
  }
  for (int i=tid;i<64;i+=stride){             // B1F = (b1-m1)*s1+be1
    float s = bn_scale(a.g1,a.v1,i);
    ws[WS_B1F+i] = (a.b1[i] - a.m1[i])*s + a.be1[i];
  }
  for (int i=tid;i<8192;i+=stride){           // W2T[c][o] = w2[o][c]*s2[o]
    int c=i>>7, o=i&127;
    ws[WS_W2T+i] = a.w2[o*64+c] * bn_scale(a.g2,a.v2,o);
  }
  for (int i=tid;i<128;i+=stride){
    float s = bn_scale(a.g2,a.v2,i);
    ws[WS_B2F+i] = (a.b2[i] - a.m2[i])*s + a.be2[i];
  }
  for (int i=tid;i<16384;i+=stride){          // W3F[c][j] = w3[j][c]*s3[j]
    int c=i>>7, j=i&127;
    ws[WS_W3F+i] = a.w3[j*128+c] * bn_scale(a.g3,a.v3,j);
  }
  for (int i=tid;i<128;i+=stride){
    float s = bn_scale(a.g3,a.v3,i);
    ws[WS_B3F+i] = (a.b3[i] - a.m3[i])*s + a.be3[i];
  }
}

// ---------------- encoder v4: 48KB LDS (h2 in quarters) -> 3 blocks/CU --------
// R7 post-mortem: VALU issue ~213us (near the 165us FMA floor) but pipe idle
// 55% at 2 waves/SIMD (64KB LDS). v4 keeps P=2 pts/lane + input-major weights
// but streams h2 through a 16KB quarter-buffer: LDS 48KB -> 3 blocks/CU.
// Accumulation chain order identical to v3 (c 0..63, c2 0..127 ascending), so
// FPS selections are bit-identical.
__global__ __launch_bounds__(256, 3) void encode_kernel(const float* __restrict__ src,
                                                        const float* __restrict__ tgt,
                                                        const float* __restrict__ ws,
                                                        float* __restrict__ lat){
  const int cloud = blockIdx.y;
  const int tile  = blockIdx.x;              // 128 tiles/cloud, 128 pts each
  const int t = threadIdx.x;
  const int lane = t & 63;
  const int wv = __builtin_amdgcn_readfirstlane(t >> 6);   // 0..3

  const float* base = ((cloud < B_) ? (src + (size_t)cloud*N_*3)
                                    : (tgt + (size_t)(cloud-B_)*N_*3))
                      + (size_t)tile*128*3;

  __shared__ float h1s[64*128];   // [c][pt]  32KB
  __shared__ float h2b[32*128];   // [q-ch][pt] 16KB (reused across quarters)

  const int p0 = 2*lane;
  const float x0a=base[p0*3+0], x1a=base[p0*3+1], x2a=base[p0*3+2];
  const float x0b=base[p0*3+3], x1b=base[p0*3+4], x2b=base[p0*3+5];

  // phase A: layer 1 (3->64); wave wv computes channels 16wv..16wv+15
  {
    const float* w1 = ws + WS_W1F;
    #pragma unroll
    for (int k=0;k<16;k++){
      const int o = wv*16 + k;
      const float wx=w1[o*3], wy=w1[o*3+1], wz=w1[o*3+2], bb=ws[WS_B1F+o];
      h1s[o*128+p0]   = fmaxf(fmaf(wz,x2a,fmaf(wy,x1a,wx*x0a))+bb, 0.0f);
      h1s[o*128+p0+1] = fmaxf(fmaf(wz,x2b,fmaf(wy,x1b,wx*x0b))+bb, 0.0f);
    }
  }
  __syncthreads();

  float accL[2][32];
  #pragma unroll
  for (int jj=0;jj<32;jj++){ accL[0][jj]=0.0f; accL[1][jj]=0.0f; }

  #pragma unroll 1
  for (int q=0;q<4;q++){
    // phase B: h2 channels [q*32 + wv*8, +8) for this lane's 2 points
    float acc2[2][8];
    #pragma unroll
    for (int oo=0;oo<8;oo++){ acc2[0][oo]=0.0f; acc2[1][oo]=0.0f; }
    const float* w2t = ws + WS_W2T + q*32 + wv*8;   // + c*128 + oo
    #pragma unroll 2
    for (int c=0;c<64;c++){
      const float2 a = *(const float2*)&h1s[c*128 + p0];
      #pragma unroll
      for (int oo=0;oo<8;oo++){
        const float w = w2t[c*128 + oo];
        acc2[0][oo] = fmaf(a.x, w, acc2[0][oo]);
        acc2[1][oo] = fmaf(a.y, w, acc2[1][oo]);
      }
    }
    __syncthreads();   // all waves done READING h2b (previous quarter)
    #pragma unroll
    for (int oo=0;oo<8;oo++){
      const float b = ws[WS_B2F + q*32 + wv*8 + oo];
      float2 y;
      y.x = fmaxf(acc2[0][oo]+b, 0.0f);
      y.y = fmaxf(acc2[1][oo]+b, 0.0f);
      *(float2*)&h2b[(wv*8+oo)*128 + p0] = y;
    }
    __syncthreads();

    // phase C: layer-3 partial over this quarter's 32 input channels
    #pragma unroll 2
    for (int c2=0;c2<32;c2++){
      const float2 a = *(const float2*)&h2b[c2*128 + p0];
      const float* wr = ws + WS_W3F + (q*32+c2)*128 + wv*32;
      #pragma unroll
      for (int jj=0;jj<32;jj++){
        const float w = wr[jj];
        accL[0][jj] = fmaf(a.x, w, accL[0][jj]);
        accL[1][jj] = fmaf(a.y, w, accL[1][jj]);
      }
    }
  }

  // bias+relu, max over 2 pts, wave-reduce 64 lanes, one atomic per channel
  #pragma unroll
  for (int jj=0;jj<32;jj++){
    const float b = ws[WS_B3F + wv*32 + jj];
    float x = fmaxf(fmaxf(accL[0][jj]+b, 0.0f), fmaxf(accL[1][jj]+b, 0.0f));
    #pragma unroll
    for (int off=32; off>0; off>>=1) x = fmaxf(x, __shfl_down(x, off, 64));
    if (lane==0)
      atomicMax((unsigned*)(lat + cloud*128 + wv*32 + jj), __float_as_uint(x));
  }
}

// ---------------- FPS + fused kp-MLP + fused src min/max ----------------------
// One block (512 thr) per cloud. Argmax: LDS dump + single-wave butterfly
// (2 barriers/round vs 16 in the old tree). Tie-break: larger v, then smaller
// index == numpy argmax first-occurrence.
__global__ __launch_bounds__(512) void fps_kernel(const float* __restrict__ src,
                                                  const float* __restrict__ tgt,
                                                  const float* __restrict__ kw1,
                                                  const float* __restrict__ kb1,
                                                  const float* __restrict__ kw2,
                                                  const float* __restrict__ kb2,
                                                  float* ws, float* out){
  const int cloud = blockIdx.x; const int t = threadIdx.x;
  const float* base = (cloud < B_) ? (src + (size_t)cloud*N_*3)
                                   : (tgt + (size_t)(cloud-B_)*N_*3);
  __shared__ float kpl[48];
  __shared__ float h[128];
  __shared__ float rv[512]; __shared__ int ri[512];
  __shared__ float sel[3];

  // fused kp MLP: lat(128) -> 128 relu -> 48  (same fmaf chains as before)
  const float* lat = ws + WS_LAT + cloud*128;
  if (t < 128){
    float acc = kb1[t];
    const float* w = kw1 + t*128;
    for (int c=0;c<128;c++) acc = fmaf(lat[c], w[c], acc);
    h[t] = fmaxf(acc, 0.0f);
  }
  __syncthreads();
  if (t < 48){
    float acc = kb2[t];
    const float* w = kw2 + t*128;
    for (int c=0;c<128;c++) acc = fmaf(h[c], w[c], acc);
    kpl[t] = acc;
  }
  __syncthreads();

  // phase A: d0 = min over proposed kps, argmax; src clouds also min/max
  float mnx=3.4e38f,mny=3.4e38f,mnz=3.4e38f, mxx=-3.4e38f,mxy=-3.4e38f,mxz=-3.4e38f;
  float bv = -1.0f; int bi = 0;
  for (int k=0;k<32;k++){
    int n = t + k*512;
    float px=base[n*3], py=base[n*3+1], pz=base[n*3+2];
    if (cloud < B_){
      mnx=fminf(mnx,px); mny=fminf(mny,py); mnz=fminf(mnz,pz);
      mxx=fmaxf(mxx,px); mxy=fmaxf(mxy,py); mxz=fmaxf(mxz,pz);
    }
    float dmin = 3.4028235e38f;
    #pragma unroll
    for (int j=0;j<K_;j++)
      dmin = fminf(dmin, dist2rn(px,py,pz, kpl[j*3],kpl[j*3+1],kpl[j*3+2]));
    if (dmin > bv){ bv = dmin; bi = n; }
  }

  // block argmax -> sel, also store keypoint 0
  rv[t]=bv; ri[t]=bi;
  __syncthreads();
  if (t < 64){
    float v = rv[t]; int i = ri[t];
    #pragma unroll
    for (int e=1;e<8;e++){
      float v2=rv[t+64*e]; int i2=ri[t+64*e];
      if (v2 > v || (v2 == v && i2 < i)){ v=v2; i=i2; }
    }
    #pragma unroll
    for (int m=1;m<64;m<<=1){
      float v2=__shfl_xor(v,m,64); int i2=__shfl_xor(i,m,64);
      if (v2 > v || (v2 == v && i2 < i)){ v=v2; i=i2; }
    }
    if (t==0){
      sel[0]=base[i*3]; sel[1]=base[i*3+1]; sel[2]=base[i*3+2];
      float* sw = ws + WS_SEL + cloud*48;
      sw[0]=sel[0]; sw[1]=sel[1]; sw[2]=sel[2];
      size_t o = (cloud<B_) ? (size_t)(OUT_SRCKP + cloud*48) : (size_t)(OUT_TGTKP + (cloud-B_)*48);
      out[o]=sel[0]; out[o+1]=sel[1]; out[o+2]=sel[2];
    }
  }
  __syncthreads();

  // src-cloud min/max block reductions (exact regardless of order)
  if (cloud < B_){
    float vals[6] = {mnx,mny,mnz,mxx,mxy,mxz};
    for (int c=0;c<6;c++){
      rv[t]=vals[c];
      __syncthreads();
      if (t < 64){
        float v = rv[t];
        #pragma unroll
        for (int e=1;e<8;e++){
          float v2 = rv[t+64*e];
          v = (c<3) ? fminf(v,v2) : fmaxf(v,v2);
        }
        #pragma unroll
        for (int m=1;m<64;m<<=1){
          float v2=__shfl_xor(v,m,64);
          v = (c<3) ? fminf(v,v2) : fmaxf(v,v2);
        }
        if (t==0){
          if (c<3) ws[WS_PMIN + cloud*3 + c] = v;
          else     ws[WS_PMAX + cloud*3 + (c-3)] = v;
        }
      }
      __syncthreads();
    }
  }

  float s0=sel[0], s1=sel[1], s2=sel[2];

  // phase B: mind = dist to sel0 (fresh, per reference), track argmax
  float mind[32];
  bv = -1.0f; bi = 0;
  #pragma unroll
  for (int k=0;k<32;k++){
    int n = t + k*512;
    float px=base[n*3], py=base[n*3+1], pz=base[n*3+2];
    float d = dist2rn(px,py,pz, s0,s1,s2);
    mind[k]=d;
    if (d > bv){ bv=d; bi=n; }
  }

  for (int it=1; it<K_; it++){
    rv[t]=bv; ri[t]=bi;
    __syncthreads();
    if (t < 64){
      float v = rv[t]; int i = ri[t];
      #pragma unroll
      for (int e=1;e<8;e++){
        float v2=rv[t+64*e]; int i2=ri[t+64*e];
        if (v2 > v || (v2 == v && i2 < i)){ v=v2; i=i2; }
      }
      #pragma unroll
      for (int m=1;m<64;m<<=1){
        float v2=__shfl_xor(v,m,64); int i2=__shfl_xor(i,m,64);
        if (v2 > v || (v2 == v && i2 < i)){ v=v2; i=i2; }
      }
      if (t==0){
        sel[0]=base[i*3]; sel[1]=base[i*3+1]; sel[2]=base[i*3+2];
        float* sw = ws + WS_SEL + cloud*48 + it*3;
        sw[0]=sel[0]; sw[1]=sel[1]; sw[2]=sel[2];
        size_t o = (cloud<B_) ? (size_t)(OUT_SRCKP + cloud*48 + it*3)
                              : (size_t)(OUT_TGTKP + (cloud-B_)*48 + it*3);
        out[o]=sel[0]; out[o+1]=sel[1]; out[o+2]=sel[2];
      }
    }
    __syncthreads();
    s0=sel[0]; s1=sel[1]; s2=sel[2];
    if (it < K_-1){
      bv=-1.0f; bi=0;
      #pragma unroll
      for (int k=0;k<32;k++){
        int n = t + k*512;
        float px=base[n*3], py=base[n*3+1], pz=base[n*3+2];
        float d = dist2rn(px,py,pz, s0,s1,s2);
        float m = fminf(mind[k], d);
        mind[k]=m;
        if (m > bv){ bv=m; bi=n; }
      }
    }
  }
}

// ---------------- cage MLP + corner grid (64 blocks) --------------------------
__global__ void cage_mlp_kernel(const float* __restrict__ ws,
                                const float* __restrict__ cw1, const float* __restrict__ cb1,
                                const float* __restrict__ cw2, const float* __restrict__ cb2,
                                float* __restrict__ wsm){
  const int b = blockIdx.x >> 2, part = blockIdx.x & 3;
  const int t = threadIdx.x;
  __shared__ float diff[48]; __shared__ float h[128];
  if (t<48) diff[t] = __fsub_rn(ws[WS_SEL + (B_+b)*48 + t], ws[WS_SEL + b*48 + t]);
  __syncthreads();
  if (t<128){
    const float* w = cw1 + t*48;
    float acc = cb1[t];
    for (int j=0;j<48;j++) acc = fmaf(diff[j], w[j], acc);
    h[t] = fmaxf(acc, 0.0f);
  }
  __syncthreads();
  for (int o = part*384 + t; o < part*384 + 384; o += 256){
    const float* w = cw2 + o*128;
    float acc = cb2[o];
    for (int c=0;c<128;c++) acc = fmaf(h[c], w[c], acc);
    int flat = o/3, coord = o - flat*3;
    int u = flat>>6, v=(flat>>3)&7, z=flat&7;
    int g = (coord==0)?u:((coord==1)?v:z);
    float gv = (g==7)?1.0f:(float)g*(1.0f/7.0f);
    wsm[WS_CF + b*1536 + o] = gv + acc;
  }
}

// ---------------- trilinear cage deform ---------------------------------------
__global__ __launch_bounds__(256) void deform_kernel(const float* __restrict__ src,
                                                     const float* __restrict__ ws,
                                                     float* __restrict__ out){
  const int b = blockIdx.y;
  const int n = blockIdx.x*256 + threadIdx.x;
  __shared__ float cf[1536];
  for (int i=threadIdx.x;i<1536;i+=256) cf[i] = ws[WS_CF + b*1536 + i];
  __syncthreads();

  const float* p = src + ((size_t)b*N_ + n)*3;
  float pt[3]; int id[3]; float w[3];
  #pragma unroll
  for (int c=0;c<3;c++){
    float pv = p[c];
    float mn = ws[WS_PMIN+b*3+c], mxv = ws[WS_PMAX+b*3+c];
    float denom = __fadd_rn(__fsub_rn(mxv, mn), 1e-6f);
    float tc = __fmul_rn(__fdiv_rn(__fsub_rn(pv, mn), denom), 7.0f);
    int ic = (int)tc; ic = min(max(ic,0),6);
    pt[c]=pv; id[c]=ic; w[c]=__fsub_rn(tc, (float)ic);
  }
  const int flat = (id[0]<<6) + (id[1]<<3) + id[2];
  const float* c000 = cf + flat*3;
  const float wx=w[0], wy=w[1], wz=w[2];
  const float ux=__fsub_rn(1.0f,wx), uy=__fsub_rn(1.0f,wy), uz=__fsub_rn(1.0f,wz);
  const float w000=__fmul_rn(__fmul_rn(ux,uy),uz);
  const float w100=__fmul_rn(__fmul_rn(wx,uy),uz);
  const float w010=__fmul_rn(__fmul_rn(ux,wy),uz);
  const float w110=__fmul_rn(__fmul_rn(wx,wy),uz);
  const float w001=__fmul_rn(__fmul_rn(ux,uy),wz);
  const float w101=__fmul_rn(__fmul_rn(wx,uy),wz);
  const float w011=__fmul_rn(__fmul_rn(ux,wy),wz);
  const float w111=__fmul_rn(__fmul_rn(wx,wy),wz);
  #pragma unroll
  for (int c=0;c<3;c++){
    float d = __fmul_rn(w000, c000[c]);
    d = __fadd_rn(d, __fmul_rn(w100, c000[192+c]));  // (+1,0,0) -> +64*3
    d = __fadd_rn(d, __fmul_rn(w010, c000[24+c]));   // (0,+1,0) -> +8*3
    d = __fadd_rn(d, __fmul_rn(w110, c000[216+c]));
    d = __fadd_rn(d, __fmul_rn(w001, c000[3+c]));    // (0,0,+1) -> +3
    d = __fadd_rn(d, __fmul_rn(w101, c000[195+c]));
    d = __fadd_rn(d, __fmul_rn(w011, c000[27+c]));
    d = __fadd_rn(d, __fmul_rn(w111, c000[219+c]));
    out[((size_t)b*N_+n)*3 + c] = __fadd_rn(pt[c], d);
  }
}

// ---------------- launch ------------------------------------------------------
extern "C" void kernel_launch(void* const* d_in, const int* in_sizes, int n_in,
                              void* d_out, int out_size, void* d_ws, size_t ws_size,
                              hipStream_t stream){
  const float* src = (const float*)d_in[0];
  const float* tgt = (const float*)d_in[1];
  float* ws = (float*)d_ws;
  float* out = (float*)d_out;

  EncW ew;
  ew.w1 =(const float*)d_in[2];  ew.b1 =(const float*)d_in[3];
  ew.g1 =(const float*)d_in[4];  ew.be1=(const float*)d_in[5];
  ew.m1 =(const float*)d_in[6];  ew.v1 =(const float*)d_in[7];
  ew.w2 =(const float*)d_in[8];  ew.b2 =(const float*)d_in[9];
  ew.g2 =(const float*)d_in[10]; ew.be2=(const float*)d_in[11];
  ew.m2 =(const float*)d_in[12]; ew.v2 =(const float*)d_in[13];
  ew.w3 =(const float*)d_in[14]; ew.b3 =(const float*)d_in[15];
  ew.g3 =(const float*)d_in[16]; ew.be3=(const float*)d_in[17];
  ew.m3 =(const float*)d_in[18]; ew.v3 =(const float*)d_in[19];

  prep_kernel<<<128, 256, 0, stream>>>(ew, ws);
  encode_kernel<<<dim3(128,32), 256, 0, stream>>>(src, tgt, ws, ws + WS_LAT);
  fps_kernel<<<32, 512, 0, stream>>>(src, tgt,
      (const float*)d_in[20], (const float*)d_in[21],
      (const float*)d_in[22], (const float*)d_in[23], ws, out);
  cage_mlp_kernel<<<64, 256, 0, stream>>>(ws,
      (const float*)d_in[24], (const float*)d_in[25],
      (const float*)d_in[26], (const float*)d_in[27], ws);
  deform_kernel<<<dim3(64,16), 256, 0, stream>>>(src, ws, out);
}